// Round 20
// baseline (256.442 us; speedup 1.0000x reference)
//
#include <hip/hip_runtime.h>
#include <hip/hip_bf16.h>

#define NU 40000
#define ND 20000
#define NUP 40192   // 157*256
#define NDP 20224   // 79*256
#define HIDC 256
#define NHEAD 4
#define NEDGE 80000
#define CHUNK 2048
#define NCH 20      // ceil(NU/CHUNK)
#define AL4 (NU * 4)

typedef __attribute__((ext_vector_type(8))) short bf16x8;
typedef __attribute__((ext_vector_type(8))) unsigned short u16x8;
typedef __attribute__((ext_vector_type(4))) float f32x4;

static __device__ __forceinline__ float b2f(unsigned short u) {
  union { unsigned int u; float f; } x; x.u = (unsigned int)u << 16; return x.f;
}
static __device__ __forceinline__ unsigned short f2b(float f) {
  union { float f; unsigned int u; } x; x.f = f;
  unsigned int r = x.u + 0x7FFFu + ((x.u >> 16) & 1u);
  return (unsigned short)(r >> 16);
}

static __device__ __forceinline__ void gload_lds16(const void* g, void* l) {
  __builtin_amdgcn_global_load_lds((const __attribute__((address_space(1))) unsigned int*)g,
                                   (__attribute__((address_space(3))) unsigned int*)l, 16, 0, 0);
}

// ============ bf16 MFMA GEMM: C = act(A @ Bt^T + bias) ============
// BM=256 x BN=128 tile, 8 waves (512 thr), wave grid 4x2 (64x64 per wave).
// Two-range grid + dual-half within range 1 (see round 16).
// ACT 0: none, 1: relu, 2: tanh+colsum->atomicAdd(Cf[cfoff+col]) (sem),
// ACT 3: skip-mix, ACT 4: plain Cb + fused HAN alsd.
// Epilogue: 4x 64-row LDS chunks, word(lrow,c) = lrow*134 + c + 2*(c>>5).
// Cb stores are guarded by col < N (lets ldcb == N < 128-tile, e.g. hb[.,64]).
template<int ACT>
__global__ __launch_bounds__(512)
void gemm_bf16(const unsigned short* __restrict__ A,
               const unsigned short* __restrict__ Bt,
               const float* __restrict__ bias,
               float* __restrict__ Cf, int ldcf,
               unsigned short* __restrict__ Cb, int ldcb,
               int M, int N, int K, int Mblk,
               const float* __restrict__ skipp,
               const unsigned short* __restrict__ xprev,
               int halfRows,
               const unsigned short* __restrict__ Bt2,
               const float* __restrict__ bias2, int M2,
               const float* __restrict__ as1, const float* __restrict__ ad1,
               const float* __restrict__ as2, const float* __restrict__ ad2,
               float* __restrict__ alsd,
               int B1,
               const unsigned short* __restrict__ A_r2,
               const unsigned short* __restrict__ Bt_r2,
               const float* __restrict__ bias_r2,
               unsigned short* __restrict__ Cb_r2, int ldcb_r2,
               int M_r2, int N_r2, int Mblk_r2)
{
  __shared__ __attribute__((aligned(128))) unsigned char smem[49152]; // A 32K + B 16K
  unsigned short* ldsA = (unsigned short*)smem;
  unsigned short* ldsB = ldsA + 16384;
  float* ldsE = (float*)smem;   // epilogue overlay: 64 rows x 134 words = 34304B

  int flat = blockIdx.x;
  const unsigned short* Ap = A;
  const unsigned short* Btp = Bt;
  const float* biasp = bias;
  float* Cfp = Cf;
  unsigned short* Cbp = Cb;
  int ldcbp = ldcb, Mp = M, Np = N, Mblkp = Mblk;
  if (flat >= B1) {
    flat -= B1;
    Ap = A_r2; Btp = Bt_r2; biasp = bias_r2; Cbp = Cb_r2; ldcbp = ldcb_r2;
    Mp = M_r2; Np = N_r2; Mblkp = Mblk_r2; Cfp = nullptr;
  }

  const int Nx = (Np + 127) >> 7;
  const int S = Nx << 3;
  const int jj = flat % S, kq = flat / S;
  const int bx = jj >> 3, by = (kq << 3) + (jj & 7);
  if (by >= Mblkp) return;

  const int tid  = threadIdx.x;
  const int lane = tid & 63, wv = tid >> 6;
  const int row0 = by * 256, col0 = bx * 128;

  const unsigned short* Btu = Btp;
  const float* biasu = biasp;
  int Mu = Mp;
  int cfoff = 0;
  if (row0 >= halfRows) { Btu = Bt2; biasu = bias2; Mu = M2; cfoff = 64; }

  const int rl = lane >> 3;
  const int sS = (lane & 7) ^ rl;

  const int lr = lane & 15, lk = lane >> 4;
  const int wr = wv >> 1, wc = wv & 1;
  const int swz = lr & 7;

  f32x4 acc[4][4] = {};

  for (int k0 = 0; k0 < K; k0 += 64) {
#pragma unroll
    for (int i = 0; i < 4; i++) {          // A: 8 waves x 32 rows = 256
      size_t ga = (size_t)(row0 + wv * 32 + i * 8 + rl) * K + k0 + sS * 8;
      gload_lds16(Ap + ga, ldsA + wv * 2048 + i * 512);
    }
#pragma unroll
    for (int i = 0; i < 2; i++) {          // B: 8 waves x 16 rows = 128
      size_t gb = (size_t)(col0 + wv * 16 + i * 8 + rl) * K + k0 + sS * 8;
      gload_lds16(Btu + gb, ldsB + wv * 1024 + i * 512);
    }
    __syncthreads();
#pragma unroll
    for (int half = 0; half < 2; half++) {
      const int k8 = half * 4 + lk;
      const int so = (k8 ^ swz) << 3;
      bf16x8 av[4], bv[4];
#pragma unroll
      for (int m = 0; m < 4; m++)
        av[m] = *(const bf16x8*)&ldsA[(wr * 64 + m * 16 + lr) * 64 + so];
#pragma unroll
      for (int n = 0; n < 4; n++)
        bv[n] = *(const bf16x8*)&ldsB[(wc * 64 + n * 16 + lr) * 64 + so];
#pragma unroll
      for (int m = 0; m < 4; m++)
#pragma unroll
        for (int n = 0; n < 4; n++)
          acc[m][n] = __builtin_amdgcn_mfma_f32_16x16x32_bf16(av[m], bv[n], acc[m][n], 0, 0, 0);
    }
    __syncthreads();
  }

  if (ACT == 2) {
    __shared__ float csum[64];
    if (tid < 64) csum[tid] = 0.f;
    __syncthreads();
#pragma unroll
    for (int n = 0; n < 4; n++) {
      int col = col0 + wc * 64 + n * 16 + lr;
      if (col < Np) {
        float bi = biasu[col];
        float local = 0.f;
#pragma unroll
        for (int m = 0; m < 4; m++)
#pragma unroll
          for (int g = 0; g < 4; g++) {
            int row = row0 + wr * 64 + m * 16 + lk * 4 + g;
            if (row < Mu) local += tanhf(acc[m][n][g] + bi);
          }
        atomicAdd(&csum[col], local);
      }
    }
    __syncthreads();
    if (tid < 64) atomicAdd(&Cfp[cfoff + tid], csum[tid]);
    return;
  }

  float su = 0.f;
  if (ACT == 3) su = 1.f / (1.f + expf(-skipp[0]));
  float bi[4];
#pragma unroll
  for (int n = 0; n < 4; n++) {
    int col = col0 + wc * 64 + n * 16 + lr;
    bi[n] = (col < Np) ? biasu[col] : 0.f;
  }

#pragma unroll
  for (int ch = 0; ch < 4; ch++) {
    __syncthreads();
    if (wr == ch) {
#pragma unroll
      for (int m = 0; m < 4; m++)
#pragma unroll
        for (int n = 0; n < 4; n++) {
          int c = wc * 64 + n * 16 + lr;
          int wbase = c + 2 * (c >> 5);
#pragma unroll
          for (int g = 0; g < 4; g++) {
            int lrow = m * 16 + lk * 4 + g;
            ldsE[lrow * 134 + wbase] = acc[m][n][g] + bi[n];
          }
        }
    }
    __syncthreads();
#pragma unroll
    for (int i = 0; i < 2; i++) {
      int c = tid + i * 512;            // 0..1023 over 64 rows x 16 col-chunks
      int lrow = c >> 4, cc = c & 15;
      int row = row0 + ch * 64 + lrow;
      int colb = cc * 8;
      int base = lrow * 134 + 8 * cc + 2 * (cc >> 2);
      float v[8];
#pragma unroll
      for (int q2 = 0; q2 < 4; q2++) {
        float2 tv = *(const float2*)&ldsE[base + 2 * q2];
        v[2 * q2] = tv.x; v[2 * q2 + 1] = tv.y;
      }
      if (ACT == 1) {
#pragma unroll
        for (int q = 0; q < 8; q++) v[q] = fmaxf(v[q], 0.f);
      }
      if (ACT == 3) {
        u16x8 xp = *(const u16x8*)(xprev + (size_t)row * 256 + col0 + colb);
#pragma unroll
        for (int q = 0; q < 8; q++) v[q] = su * v[q] + (1.f - su) * b2f(xp[q]);
      }
      if (ACT == 4) {
        if (colb < 64 && row < Mu) {
          int hh = colb >> 4;
          int o0 = colb & 15;
          float s1 = 0, d1 = 0, s2 = 0, d2 = 0;
#pragma unroll
          for (int q = 0; q < 8; q++) {
            float x = v[q];
            s1 += x * as1[hh * 16 + o0 + q];
            d1 += x * ad1[hh * 16 + o0 + q];
            s2 += x * as2[hh * 16 + o0 + q];
            d2 += x * ad2[hh * 16 + o0 + q];
          }
          s1 += __shfl_xor(s1, 1); d1 += __shfl_xor(d1, 1);
          s2 += __shfl_xor(s2, 1); d2 += __shfl_xor(d2, 1);
          if ((lane & 1) == 0) {
            size_t idx = (size_t)row * 4 + hh;
            alsd[idx]           = s1;
            alsd[AL4 + idx]     = d1;
            alsd[2 * AL4 + idx] = s2;
            alsd[3 * AL4 + idx] = d2;
          }
        }
      }
      if (Cbp) {
        int col = col0 + colb;
        if (col < Np) {
          u16x8 o;
#pragma unroll
          for (int q = 0; q < 8; q++) o[q] = f2b(row < Mu ? v[q] : 0.f);
          *(u16x8*)(Cbp + (size_t)row * ldcbp + col) = o;
        }
      }
      if (Cfp && row < Mu) {
        int col = col0 + colb;
        if (col < Np)
          *(float4*)&Cfp[(size_t)row * ldcf + col] = make_float4(v[0], v[1], v[2], v[3]);
        if (col + 4 < Np)
          *(float4*)&Cfp[(size_t)row * ldcf + col + 4] = make_float4(v[4], v[5], v[6], v[7]);
      }
    }
  }
}

// ============ fused prep (block-granular; small regions FIRST, streaming conv LAST) ============
// regions: comb [0,16), bias [16,21), zero-cnt [21,139), transp [139,1323), conv [1323,7611)
__global__ __launch_bounds__(256)
void prep_all(const float* __restrict__ x_user, const float* __restrict__ x_drug,
              const float* __restrict__ x_user_ref,
              const float* __restrict__ W_in_user, const float* __restrict__ W_in_drug,
              const float* __restrict__ W_kqv_user, const float* __restrict__ W_kqv_drug,
              const float* __restrict__ W_out_user, const float* __restrict__ W_fin,
              const float* __restrict__ W_han, const float* __restrict__ Wk_sem,
              const float* __restrict__ Wk_uu, const float* __restrict__ Wv_uu,
              const float* __restrict__ Wk_du, const float* __restrict__ Wv_du,
              const float* __restrict__ b_kqv_user, const float* __restrict__ b_kqv_drug,
              unsigned short* __restrict__ xub, unsigned short* __restrict__ xdb,
              unsigned short* __restrict__ xrb,
              unsigned short* __restrict__ Btu_in, unsigned short* __restrict__ Btd_in,
              unsigned short* __restrict__ Btall_u, unsigned short* __restrict__ Btall_d,
              unsigned short* __restrict__ Bto, unsigned short* __restrict__ Btf,
              unsigned short* __restrict__ Bth, unsigned short* __restrict__ BtWk,
              float* __restrict__ ball_u, float* __restrict__ ball_d,
              int* __restrict__ cnt)
{
  __shared__ float sWh[4096];      // 16KB
  __shared__ float sWk[64][65];    // 16.6KB
  const int b = blockIdx.x;
  const int tid = threadIdx.x;

  if (b < 16) {  // comb x16: block = (mat, hh); LDS-tiled, 4 ctiles of 64 cols
    int mat = b >> 2, hh = b & 3;
    const float* Wkqv; const float* Wh; unsigned short* Bt; int coloff;
    switch (mat) {
      case 0:  Wkqv = W_kqv_user; Wh = Wk_uu; Bt = Btall_u;          coloff = 0;   break;
      case 1:  Wkqv = W_kqv_user; Wh = Wv_uu; Bt = Btall_u + 131072; coloff = 512; break;
      case 2:  Wkqv = W_kqv_drug; Wh = Wk_du; Bt = Btall_d;          coloff = 0;   break;
      default: Wkqv = W_kqv_drug; Wh = Wv_du; Bt = Btall_d + 65536;  coloff = 512; break;
    }
    for (int i = tid; i < 4096; i += 256) sWh[i] = Wh[hh * 4096 + i];
    __syncthreads();
    for (int ct = 0; ct < 4; ct++) {
      for (int i = tid; i < 4096; i += 256) {
        int cl = i >> 6, d = i & 63;
        sWk[cl][d] = Wkqv[(size_t)(ct * 64 + cl) * 768 + coloff + hh * 64 + d];
      }
      __syncthreads();
      int cl = tid & 63, eg = tid >> 6;
      float acc[16] = {};
      for (int d = 0; d < 64; d++) {
        float w = sWk[cl][d];
#pragma unroll
        for (int e = 0; e < 16; e++) acc[e] += w * sWh[d * 64 + eg * 16 + e];
      }
#pragma unroll
      for (int e = 0; e < 16; e++)
        Bt[(size_t)(hh * 64 + eg * 16 + e) * 256 + ct * 64 + cl] = f2b(acc[e]);
      __syncthreads();
    }
    return;
  }
  if (b < 21) {  // biases (5 blocks x 256 = 1280)
    int j = (b - 16) * 256 + tid;
    const float* bb; const float* Wh; float* outp; int coloff, e256;
    if (j < 256)       { outp = &ball_u[j];        bb = b_kqv_user; Wh = Wk_uu; coloff = 0;   e256 = j; }
    else if (j < 512)  { ball_u[j] = b_kqv_user[j]; return; }
    else if (j < 768)  { outp = &ball_u[j];        bb = b_kqv_user; Wh = Wv_uu; coloff = 512; e256 = j - 512; }
    else if (j < 1024) { outp = &ball_d[j - 768];  bb = b_kqv_drug; Wh = Wk_du; coloff = 0;   e256 = j - 768; }
    else               { outp = &ball_d[j - 768];  bb = b_kqv_drug; Wh = Wv_du; coloff = 512; e256 = j - 1024; }
    int hh = e256 >> 6, e = e256 & 63;
    float acc = 0.f;
    for (int d = 0; d < 64; d++)
      acc += bb[coloff + hh * 64 + d] * Wh[hh * 4096 + d * 64 + e];
    *outp = acc;
    return;
  }
  if (b < 139) {  // zero cnt (3*NU = 120000 ints -> 30000 int4 units; 118 blocks)
    int u = (b - 21) * 256 + tid;
    int idx = u * 4;
    if (idx < 3 * NU) *(int4*)&cnt[idx] = make_int4(0, 0, 0, 0);
    return;
  }
  if (b < 1323) {  // transp_conv x7 (scalar; small, L2-resident)
    size_t i = (size_t)(b - 139) * 256 + tid;
    const float* W; unsigned short* Bt; int ldw, coloff, K, N;
    if (i < 32768)       { W = W_in_user;  Bt = Btu_in;          ldw = 256; coloff = 0;   K = 128; N = 256; }
    else if (i < 65536)  { W = W_in_drug;  Bt = Btd_in;          ldw = 256; coloff = 0;   K = 128; N = 256; i -= 32768; }
    else if (i < 131072) { W = W_kqv_user; Bt = Btall_u + 65536; ldw = 768; coloff = 256; K = 256; N = 256; i -= 65536; }
    else if (i < 196608) { W = W_out_user; Bt = Bto;             ldw = 256; coloff = 0;   K = 256; N = 256; i -= 131072; }
    else if (i < 278528) { W = W_fin;      Bt = Btf;             ldw = 256; coloff = 0;   K = 320; N = 256; i -= 196608; }
    else if (i < 294912) { W = W_han;      Bt = Bth;             ldw = 64;  coloff = 0;   K = 128; N = 64;  i -= 278528; }
    else                 { W = Wk_sem;     Bt = BtWk;            ldw = 64;  coloff = 0;   K = 64;  N = 64;  i -= 294912; }
    int n = (int)(i / K), k = (int)(i - (size_t)n * K);
    Bt[i] = (n < N) ? f2b(W[(size_t)k * ldw + coloff + n]) : 0;
    return;
  }
  {  // vectorized conv_pad x3 (uniform streaming tail)
    int bc = b - 1323;
    const float* in; unsigned short* outp; int M; int bl;
    if (bc < 2512)      { in = x_user;     outp = xub; M = NU; bl = bc; }
    else if (bc < 3776) { in = x_drug;     outp = xdb; M = ND; bl = bc - 2512; }
    else                { in = x_user_ref; outp = xrb; M = NU; bl = bc - 3776; }
    size_t e0 = ((size_t)bl * 256 + tid) * 8;
    int r = (int)(e0 >> 7);
    u16x8 o;
    if (r < M) {
      float4 a = *(const float4*)(in + e0);
      float4 bb = *(const float4*)(in + e0 + 4);
      o[0] = f2b(a.x); o[1] = f2b(a.y); o[2] = f2b(a.z); o[3] = f2b(a.w);
      o[4] = f2b(bb.x); o[5] = f2b(bb.y); o[6] = f2b(bb.z); o[7] = f2b(bb.w);
    } else {
#pragma unroll
      for (int q = 0; q < 8; q++) o[q] = 0;
    }
    *(u16x8*)(outp + e0) = o;
  }
}

// ============ CSR build ============
__global__ void hist_all(const int* __restrict__ ei_du, const int* __restrict__ ei_uu,
                         const int* __restrict__ ei_r1, const int* __restrict__ ei_r2,
                         int* __restrict__ cnt)
{
  int t = blockIdx.x * 256 + threadIdx.x;
  if (t >= NEDGE) return;
  const int* ei; int* c;
  switch (blockIdx.y) {
    case 0: ei = ei_du; c = cnt; break;
    case 1: ei = ei_uu; c = cnt; break;
    case 2: ei = ei_r1; c = cnt + NU; break;
    default: ei = ei_r2; c = cnt + 2 * NU; break;
  }
  atomicAdd(&c[ei[NEDGE + t]], 1);
}

__global__ __launch_bounds__(256)
void scan_partial(const int* __restrict__ cnt, int* __restrict__ csums)
{
  int b = blockIdx.x;
  int rel = b / NCH, ch = b - rel * NCH;
  const int* c = cnt + (size_t)rel * NU;
  int t = threadIdx.x;
  int i0 = ch * CHUNK + t * 8;
  int s = 0;
#pragma unroll
  for (int j = 0; j < 8; j++) { int i = i0 + j; if (i < NU) s += c[i]; }
  __shared__ int ps[256];
  ps[t] = s;
  __syncthreads();
  for (int d = 128; d > 0; d >>= 1) { if (t < d) ps[t] += ps[t + d]; __syncthreads(); }
  if (t == 0) csums[b] = ps[0];
}

// also zeroes colpart2
__global__ void scan_mid(const int* __restrict__ csums, int* __restrict__ coffs,
                         int* __restrict__ rs, float* __restrict__ colpart2)
{
  int r = threadIdx.x;   // 128 threads
  if (r < 128) colpart2[r] = 0.f;
  if (r >= 3) return;
  int run = 0;
  for (int ch = 0; ch < NCH; ch++) { coffs[r * NCH + ch] = run; run += csums[r * NCH + ch]; }
  rs[(size_t)r * NUP + NU] = run;
}

// zeroes cnt after reading (cursor reset)
__global__ __launch_bounds__(256)
void scan_final(int* __restrict__ cnt, const int* __restrict__ coffs,
                int* __restrict__ rs)
{
  int b = blockIdx.x;
  int rel = b / NCH, ch = b - rel * NCH;
  int* c = cnt + (size_t)rel * NU;
  int* r = rs + (size_t)rel * NUP;
  int t = threadIdx.x;
  int i0 = ch * CHUNK + t * 8;
  int loc[8]; int s = 0;
#pragma unroll
  for (int j = 0; j < 8; j++) {
    int i = i0 + j;
    loc[j] = (i < NU) ? c[i] : 0;
    if (i < NU) c[i] = 0;
    s += loc[j];
  }
  __shared__ int ps[256];
  ps[t] = s;
  __syncthreads();
  for (int d = 1; d < 256; d <<= 1) {
    int o = (t >= d) ? ps[t - d] : 0;
    __syncthreads();
    ps[t] += o;
    __syncthreads();
  }
  int run = coffs[b] + ps[t] - s;
#pragma unroll
  for (int j = 0; j < 8; j++) { int i = i0 + j; if (i < NU) { r[i] = run; run += loc[j]; } }
}

// ============ merged fills: y=0 han r1, y=1 han r2, y=2 hgt du, y=3 hgt uu ============
// HGT halves are index-scatter only: esrcH[pos] = kbase|type (k-row offset
// in qukvb ushort units; type bit 0: 0=du, 1=uu). QK moved to gather.
__global__ void fill_all(const int* __restrict__ ei_r1, const int* __restrict__ ei_r2,
                         const int* __restrict__ ei_du, const int* __restrict__ ei_uu,
                         const float* __restrict__ alsd,
                         const int* __restrict__ rs, int* __restrict__ cur,
                         int* __restrict__ esrc1, float* __restrict__ aev1,
                         int* __restrict__ esrc2, float* __restrict__ aev2,
                         int* __restrict__ esrcH)
{
  int t = blockIdx.x * 256 + threadIdx.x;
  if (t >= NEDGE * 4) return;
  int y = blockIdx.y;
  int e = t >> 2, hh = t & 3;
  if (y < 2) {
    const int* ei = y ? ei_r2 : ei_r1;
    const float* als = alsd + (y ? 2 * AL4 : 0);
    const float* ald = alsd + (y ? 3 * AL4 : AL4);
    const int* rsp = rs + (size_t)(y ? 2 : 1) * NUP;
    int* curp = cur + (size_t)(y ? 2 : 1) * NU;
    int* esrc = y ? esrc2 : esrc1;
    float* aev = y ? aev2 : aev1;
    int s = ei[e], d = ei[NEDGE + e];
    float al = als[s * 4 + hh] + ald[d * 4 + hh];
    al = (al >= 0.f) ? al : 0.2f * al;
    float ex = expf(al);
    int pos = 0;
    if (hh == 0) pos = rsp[d] + atomicAdd(&curp[d], 1);
    pos = __shfl(pos, (threadIdx.x & 63) & ~3, 64);
    aev[pos * 4 + hh] = ex;
    if (hh == 0) esrc[pos] = s;
  } else {
    if (hh != 0) return;
    int yy = y - 2;
    const int* ei = yy ? ei_uu : ei_du;
    int s = ei[e], d = ei[NEDGE + e];
    int pos = rs[d] + atomicAdd(&cur[d], 1);
    int kb = yy ? ((s * 768) | 1) : (NUP * 768 + s * 512);
    esrcH[pos] = kb;
  }
}

// ============ merged gathers: y=0 obf1, y=1 obf2, y=2 hout ============
// y<2: single-pass weighted-mean, batch-4 MLP unroll.
// y=2: fused QK dot (16-lane shuffle reduce) + softmax + PV + GELU.
// Dead batch slots skipped via WAVE-UNIFORM branches (beg/end uniform) —
// no wasted loads/compute, MLP preserved for live slots.
__global__ __launch_bounds__(256)
void gather_all(const int* __restrict__ rs,
                const int* __restrict__ esrc1, const float* __restrict__ aev1,
                const int* __restrict__ esrc2, const float* __restrict__ aev2,
                const int* __restrict__ esrcH,
                const unsigned short* __restrict__ hb,
                const unsigned short* __restrict__ vbase,
                const float* __restrict__ p_du, const float* __restrict__ p_uu,
                unsigned short* __restrict__ obf1, unsigned short* __restrict__ obf2,
                unsigned short* __restrict__ houtb)
{
  int gid = blockIdx.x * 256 + threadIdx.x;
  int wid = gid >> 6, lane = gid & 63;
  if (wid >= NUP) return;
  int y = blockIdx.y;
  int head = lane >> 4;
  if (y < 2) {
    const int* rsp = rs + (size_t)(y ? 2 : 1) * NUP;
    const int* esrc = y ? esrc2 : esrc1;
    const float* aev = y ? aev2 : aev1;
    unsigned short* obf = y ? obf2 : obf1;
    int beg = 0, end = 0;
    if (wid < NU) { beg = rsp[wid]; end = rsp[wid + 1]; }
    float asum = 0.f, a = 0.f;
    for (int i0 = beg; i0 < end; i0 += 4) {
      int nrem = end - i0;               // wave-uniform
      int idx[4]; float w[4];
      float hv[4];
#pragma unroll
      for (int u = 0; u < 4; u++) {
        if (u < nrem) {
          idx[u] = esrc[i0 + u];
          w[u] = aev[(i0 + u) * 4 + head];
        }
      }
#pragma unroll
      for (int u = 0; u < 4; u++) {
        if (u < nrem)
          hv[u] = b2f(hb[(size_t)idx[u] * 64 + lane]);
      }
#pragma unroll
      for (int u = 0; u < 4; u++) {
        if (u < nrem) { asum += w[u]; a += w[u] * hv[u]; }
      }
    }
    a *= 1.f / (asum + 1e-16f);
    obf[(size_t)wid * 64 + lane] = f2b(fmaxf(a, 0.f));
  } else {
    int beg = 0, end = 0;
    if (wid < NU) { beg = rs[wid]; end = rs[wid + 1]; }
    // q[d] row: lane covers its head's 4 columns (coalesced, once per wave)
    ushort4 qv = *(const ushort4*)(vbase + (size_t)wid * 768 + 256 + lane * 4);
    float q0 = b2f(qv.x), q1 = b2f(qv.y), q2 = b2f(qv.z), q3 = b2f(qv.w);
    float pd = p_du[head] * 0.125f, pu = p_uu[head] * 0.125f;
    float asum = 0.f;
    float a0 = 0, a1 = 0, a2 = 0, a3 = 0;
    for (int i0 = beg; i0 < end; i0 += 4) {
      int nrem = end - i0;               // wave-uniform
      int kb[4];
      ushort4 kk[4], vv[4];
#pragma unroll
      for (int u = 0; u < 4; u++) {
        if (u < nrem) kb[u] = esrcH[i0 + u];
      }
#pragma unroll
      for (int u = 0; u < 4; u++) {
        if (u < nrem) {
          int base = kb[u] & ~1;
          int type = kb[u] & 1;
          kk[u] = *(const ushort4*)(vbase + (size_t)base + lane * 4);
          vv[u] = *(const ushort4*)(vbase + (size_t)(base + 256 + 256 * type) + lane * 4);
        }
      }
#pragma unroll
      for (int u = 0; u < 4; u++) {
        if (u < nrem) {
          float part = q0 * b2f(kk[u].x) + q1 * b2f(kk[u].y)
                     + q2 * b2f(kk[u].z) + q3 * b2f(kk[u].w);
          part += __shfl_xor(part, 1, 16);
          part += __shfl_xor(part, 2, 16);
          part += __shfl_xor(part, 4, 16);
          part += __shfl_xor(part, 8, 16);
          float pp = (kb[u] & 1) ? pu : pd;
          float w = expf(part * pp);
          asum += w;
          a0 += b2f(vv[u].x) * w; a1 += b2f(vv[u].y) * w;
          a2 += b2f(vv[u].z) * w; a3 += b2f(vv[u].w) * w;
        }
      }
    }
    float inv = 1.f / (asum + 1e-16f);
    a0 *= inv; a1 *= inv; a2 *= inv; a3 *= inv;
    ushort4 o;
    o.x = f2b(0.5f * a0 * (1.f + erff(a0 * 0.70710678118654752f)));
    o.y = f2b(0.5f * a1 * (1.f + erff(a1 * 0.70710678118654752f)));
    o.z = f2b(0.5f * a2 * (1.f + erff(a2 * 0.70710678118654752f)));
    o.w = f2b(0.5f * a3 * (1.f + erff(a3 * 0.70710678118654752f)));
    *(ushort4*)(houtb + (size_t)wid * 256 + lane * 4) = o;
  }
}

__global__ void sem_final2(const float* __restrict__ colpart2,
                           const float* __restrict__ q_sem, float* __restrict__ semv)
{
  int t = threadIdx.x;            // 128
  int j = t & 63;
  __shared__ float sv[128];
  sv[t] = colpart2[t] * q_sem[j] * (1.0f / NU);
  __syncthreads();
  if (t == 0) {
    float s0 = 0, s1 = 0;
    for (int i = 0; i < 64; i++) { s0 += sv[i]; s1 += sv[64 + i]; }
    float m = fmaxf(s0, s1);
    float e0 = expf(s0 - m), e1 = expf(s1 - m);
    semv[0] = e0 / (e0 + e1); semv[1] = e1 / (e0 + e1);
  }
}

// ============ epilogues ============
__global__ void fill_ref_b(const unsigned short* __restrict__ obf1,
                           const unsigned short* __restrict__ obf2,
                           const float* __restrict__ semv, unsigned short* __restrict__ afinb)
{
  int t = blockIdx.x * 256 + threadIdx.x;  // n*64 + j
  if (t >= NUP * 64) return;
  int n = t >> 6, j = t & 63;
  float v = semv[0] * b2f(obf1[t]) + semv[1] * b2f(obf2[t]);  // pad rows are 0
  afinb[(size_t)n * 320 + 256 + j] = f2b(v);
}

// ------------------------------------------------------------------
extern "C" void kernel_launch(void* const* d_in, const int* in_sizes, int n_in,
                              void* d_out, int out_size, void* d_ws, size_t ws_size,
                              hipStream_t stream)
{
  (void)in_sizes; (void)n_in; (void)out_size; (void)ws_size;
  const float* x_user     = (const float*)d_in[0];
  const float* x_drug     = (const float*)d_in[1];
  const float* x_user_ref = (const float*)d_in[2];
  const int*   ei_du      = (const int*)d_in[4];
  const int*   ei_uu      = (const int*)d_in[5];
  const int*   ei_r1      = (const int*)d_in[6];
  const int*   ei_r2      = (const int*)d_in[7];
  const float* W_han      = (const float*)d_in[8];
  const float* b_han      = (const float*)d_in[9];
  const float* a_src_r1   = (const float*)d_in[10];
  const float* a_dst_r1   = (const float*)d_in[11];
  const float* a_src_r2   = (const float*)d_in[12];
  const float* a_dst_r2   = (const float*)d_in[13];
  const float* Wk_sem     = (const float*)d_in[14];
  const float* bk_sem     = (const float*)d_in[15];
  const float* q_sem      = (const float*)d_in[16];
  const float* W_in_user  = (const float*)d_in[17];
  const float* b_in_user  = (const float*)d_in[18];
  const float* W_in_drug  = (const float*)d_in[19];
  const float* b_in_drug  = (const float*)d_in[20];
  const float* W_kqv_user = (const float*)d_in[21];
  const float* b_kqv_user = (const float*)d_in[22];
  const float* W_kqv_drug = (const float*)d_in[23];
  const float* b_kqv_drug = (const float*)d_in[24];
  const float* Wk_du      = (const float*)d_in[28];
  const float* Wv_du      = (const float*)d_in[29];
  const float* p_du       = (const float*)d_in[30];
  const float* Wk_uu      = (const float*)d_in[31];
  const float* Wv_uu      = (const float*)d_in[32];
  const float* p_uu       = (const float*)d_in[33];
  const float* W_out_user = (const float*)d_in[34];
  const float* b_out_user = (const float*)d_in[35];
  const float* skip_user  = (const float*)d_in[38];
  const float* W_fin      = (const float*)d_in[40];
  const float* b_fin      = (const float*)d_in[41];
  float* out = (float*)d_out;

  // ---------------- workspace ----------------
  char* base = (char*)d_ws;
  size_t off = 0;
  auto alloc = [&](size_t bytes) { char* p = base + off; off += (bytes + 255) & ~(size_t)255; return p; };

  unsigned short* hb = (unsigned short*)alloc((size_t)NUP * 64 * 2);   // bf16 h
  float* alsd    = (float*)alloc((size_t)4 * AL4 * 4);   // als1|ald1|als2|ald2
  float* colpart2= (float*)alloc(128 * 4);
  float* semv    = (float*)alloc(64);
  float* ball_u  = (float*)alloc(768 * 4);
  float* ball_d  = (float*)alloc(512 * 4);

  int* cnt   = (int*)alloc((size_t)3 * NU * 4);
  int* rs    = (int*)alloc((size_t)3 * NUP * 4);
  int* csums = (int*)alloc((size_t)3 * NCH * 4);
  int* coffs = (int*)alloc((size_t)3 * NCH * 4);
  int* esrcH = (int*)alloc((size_t)2 * NEDGE * 4);
  int* esrc1 = (int*)alloc((size_t)NEDGE * 4);
  float* aev1= (float*)alloc((size_t)NEDGE * 4 * 4);
  int* esrc2 = (int*)alloc((size_t)NEDGE * 4);
  float* aev2= (float*)alloc((size_t)NEDGE * 4 * 4);

  unsigned short* obf1 = (unsigned short*)alloc((size_t)NUP * 64 * 2);  // contiguous with obf2
  unsigned short* obf2 = (unsigned short*)alloc((size_t)NUP * 64 * 2);

  unsigned short* qukvb = (unsigned short*)alloc((size_t)NUP * 768 * 2); // contiguous with kvdb
  unsigned short* kvdb  = (unsigned short*)alloc((size_t)NDP * 512 * 2);

  unsigned short* xub2d = (unsigned short*)alloc((size_t)NUP * 256 * 2); // contiguous with xdb2d
  unsigned short* xdb2d = (unsigned short*)alloc((size_t)NDP * 256 * 2);

  unsigned short* houtb = (unsigned short*)alloc((size_t)NUP * 256 * 2);
  unsigned short* xrb   = houtb;

  unsigned short* afinb = (unsigned short*)alloc((size_t)NUP * 320 * 2);
  unsigned short* xub   = afinb;                       // rows [0,NUP)
  unsigned short* xdb   = afinb + (size_t)NUP * 128;   // rows [NUP,NUP+NDP)

  unsigned short* Btu_in  = (unsigned short*)alloc(256 * 128 * 2);
  unsigned short* Btd_in  = (unsigned short*)alloc(256 * 128 * 2);
  unsigned short* Btall_u = (unsigned short*)alloc(768 * 256 * 2);
  unsigned short* Btall_d = (unsigned short*)alloc(512 * 256 * 2);
  unsigned short* Bto     = (unsigned short*)alloc(256 * 256 * 2);
  unsigned short* Btf     = (unsigned short*)alloc(256 * 320 * 2);
  unsigned short* Bth     = (unsigned short*)alloc(128 * 128 * 2);
  unsigned short* BtWk    = (unsigned short*)alloc(128 * 64 * 2);

  dim3 blk(256), blk5(512);
  auto g1 = [](size_t n) { return dim3((unsigned)((n + 255) / 256)); };
  auto gg = [](int N, int Mblk) {   // Mblk = number of 256-row panels
    int Nx = (N + 127) / 128;
    return (unsigned)(((Mblk + 7) / 8) * 8 * Nx);
  };
  const int BIG = 1 << 30;
  const unsigned short* NB = nullptr;
  const float* NF = nullptr;
  unsigned short* NBm = nullptr;

  // ===== fused prep: comb(16)+bias(5)+zerocnt(118)+transp(1184)+conv(6288) =====
  const int prep_blocks = 16 + 5 + 118 + 1184 + 6288;
  prep_all<<<dim3(prep_blocks), blk, 0, stream>>>(
      x_user, x_drug, x_user_ref, W_in_user, W_in_drug, W_kqv_user, W_kqv_drug,
      W_out_user, W_fin, W_han, Wk_sem, Wk_uu, Wv_uu, Wk_du, Wv_du,
      b_kqv_user, b_kqv_drug,
      xub, xdb, xrb, Btu_in, Btd_in, Btall_u, Btall_d, Bto, Btf, Bth, BtWk,
      ball_u, ball_d, cnt);

  // ===== CSR build =====
  hist_all<<<dim3((NEDGE + 255) / 256, 4), blk, 0, stream>>>(ei_du, ei_uu, ei_r1, ei_r2, cnt);
  scan_partial<<<3 * NCH, blk, 0, stream>>>(cnt, csums);
  scan_mid<<<1, 128, 0, stream>>>(csums, coffs, rs, colpart2);
  scan_final<<<3 * NCH, blk, 0, stream>>>(cnt, coffs, rs);   // zeroes cnt (cursors)

  // ===== HAN branch: h-GEMM (bf16 hb out) with fused alsd (ACT=4) =====
  gemm_bf16<4><<<gg(64, 157), blk5, 0, stream>>>(
      xrb, Bth, b_han, (float*)nullptr, 0, hb, 64, NU, 64, 128, 157,
      nullptr, nullptr, BIG, NB, NF, 0,
      a_src_r1, a_dst_r1, a_src_r2, a_dst_r2, alsd,
      BIG, NB, NB, NF, NBm, 0, 0, 0, 0);

  // ===== input GEMM: dual-half (user / drug) =====
  gemm_bf16<1><<<gg(256, 236), blk5, 0, stream>>>(
      xub, Btu_in, b_in_user, (float*)nullptr, 0, xub2d, 256, NU, 256, 128, 236,
      nullptr, nullptr, NUP, Btd_in, b_in_drug, NUP + ND,
      NF, NF, NF, NF, nullptr,
      BIG, NB, NB, NF, NBm, 0, 0, 0, 0);

  // ===== merged qukv + kvd GEMM: two-range grid =====
  {
    unsigned B1 = gg(768, 157), B2 = gg(512, 79);
    gemm_bf16<0><<<dim3(B1 + B2), blk5, 0, stream>>>(
        xub2d, Btall_u, ball_u, (float*)nullptr, 0, qukvb, 768, NU, 768, 256, 157,
        nullptr, nullptr, BIG, NB, NF, 0, NF, NF, NF, NF, nullptr,
        (int)B1, xdb2d, Btall_d, ball_d, kvdb, 512, ND, 512, 79);
  }

  // ===== merged fills (han r1/r2 exp + hgt index-scatter) =====
  fill_all<<<dim3((NEDGE * 4 + 255) / 256, 4), blk, 0, stream>>>(
      ei_r1, ei_r2, ei_du, ei_uu, alsd,
      rs, cnt, esrc1, aev1, esrc2, aev2, esrcH);

  // ===== merged gathers (obf1, obf2, hout w/ fused QK-softmax-PV) =====
  gather_all<<<dim3((NUP * 64 + 255) / 256, 3), blk, 0, stream>>>(
      rs, esrc1, aev1, esrc2, aev2, esrcH, hb, qukvb, p_du, p_uu,
      obf1, obf2, houtb);

  // ===== semantic attention =====
  gemm_bf16<2><<<gg(64, 314), blk5, 0, stream>>>(
      obf1, BtWk, bk_sem, colpart2, 0, NBm, 0, NU, 64, 64, 314,
      nullptr, nullptr, NUP, BtWk, bk_sem, NUP + NU,
      NF, NF, NF, NF, nullptr,
      BIG, NB, NB, NF, NBm, 0, 0, 0, 0);
  sem_final2<<<1, 128, 0, stream>>>(colpart2, q_sem, semv);

  // ===== output head =====
  gemm_bf16<3><<<gg(256, 157), blk5, 0, stream>>>(
      houtb, Bto, b_out_user, (float*)nullptr, 0, afinb, 320, NU, 256, 256, 157,
      skip_user, xub2d, BIG, NB, NF, 0, NF, NF, NF, NF, nullptr,
      BIG, NB, NB, NF, NBm, 0, 0, 0, 0);
  fill_ref_b<<<g1((size_t)NUP * 64), blk, 0, stream>>>(obf1, obf2, semv, afinb);

  gemm_bf16<0><<<gg(256, 157), blk5, 0, stream>>>(
      afinb, Btf, b_fin, out, 256, NBm, 0, NU, 256, 320, 157,
      nullptr, nullptr, BIG, NB, NF, 0, NF, NF, NF, NF, nullptr,
      BIG, NB, NB, NF, NBm, 0, 0, 0, 0);
}

// Round 21
// 247.353 us; speedup vs baseline: 1.0367x; 1.0367x over previous
//
#include <hip/hip_runtime.h>
#include <hip/hip_bf16.h>

#define NU 40000
#define ND 20000
#define NUP 40192   // 157*256
#define NDP 20224   // 79*256
#define HIDC 256
#define NHEAD 4
#define NEDGE 80000
#define CHUNK 2048
#define NCH 20      // ceil(NU/CHUNK)
#define AL4 (NU * 4)

typedef __attribute__((ext_vector_type(8))) short bf16x8;
typedef __attribute__((ext_vector_type(8))) unsigned short u16x8;
typedef __attribute__((ext_vector_type(4))) float f32x4;

static __device__ __forceinline__ float b2f(unsigned short u) {
  union { unsigned int u; float f; } x; x.u = (unsigned int)u << 16; return x.f;
}
static __device__ __forceinline__ unsigned short f2b(float f) {
  union { float f; unsigned int u; } x; x.f = f;
  unsigned int r = x.u + 0x7FFFu + ((x.u >> 16) & 1u);
  return (unsigned short)(r >> 16);
}

static __device__ __forceinline__ void gload_lds16(const void* g, void* l) {
  __builtin_amdgcn_global_load_lds((const __attribute__((address_space(1))) unsigned int*)g,
                                   (__attribute__((address_space(3))) unsigned int*)l, 16, 0, 0);
}

// ============ bf16 MFMA GEMM: C = act(A @ Bt^T + bias) ============
// BM=256 x BN=128 tile, 8 waves (512 thr), wave grid 4x2 (64x64 per wave).
// Two-range grid + dual-half within range 1 (see round 16).
// ACT 0: none, 1: relu, 2: tanh+colsum->atomicAdd(Cf[cfoff+col]) (sem),
// ACT 3: skip-mix, ACT 4: plain Cb + fused HAN alsd.
// Epilogue: 4x 64-row LDS chunks, word(lrow,c) = lrow*134 + c + 2*(c>>5).
// Cb stores are guarded by col < N (lets ldcb == N < 128-tile, e.g. hb[.,64]).
template<int ACT>
__global__ __launch_bounds__(512)
void gemm_bf16(const unsigned short* __restrict__ A,
               const unsigned short* __restrict__ Bt,
               const float* __restrict__ bias,
               float* __restrict__ Cf, int ldcf,
               unsigned short* __restrict__ Cb, int ldcb,
               int M, int N, int K, int Mblk,
               const float* __restrict__ skipp,
               const unsigned short* __restrict__ xprev,
               int halfRows,
               const unsigned short* __restrict__ Bt2,
               const float* __restrict__ bias2, int M2,
               const float* __restrict__ as1, const float* __restrict__ ad1,
               const float* __restrict__ as2, const float* __restrict__ ad2,
               float* __restrict__ alsd,
               int B1,
               const unsigned short* __restrict__ A_r2,
               const unsigned short* __restrict__ Bt_r2,
               const float* __restrict__ bias_r2,
               unsigned short* __restrict__ Cb_r2, int ldcb_r2,
               int M_r2, int N_r2, int Mblk_r2)
{
  __shared__ __attribute__((aligned(128))) unsigned char smem[49152]; // A 32K + B 16K
  unsigned short* ldsA = (unsigned short*)smem;
  unsigned short* ldsB = ldsA + 16384;
  float* ldsE = (float*)smem;   // epilogue overlay: 64 rows x 134 words = 34304B

  int flat = blockIdx.x;
  const unsigned short* Ap = A;
  const unsigned short* Btp = Bt;
  const float* biasp = bias;
  float* Cfp = Cf;
  unsigned short* Cbp = Cb;
  int ldcbp = ldcb, Mp = M, Np = N, Mblkp = Mblk;
  if (flat >= B1) {
    flat -= B1;
    Ap = A_r2; Btp = Bt_r2; biasp = bias_r2; Cbp = Cb_r2; ldcbp = ldcb_r2;
    Mp = M_r2; Np = N_r2; Mblkp = Mblk_r2; Cfp = nullptr;
  }

  const int Nx = (Np + 127) >> 7;
  const int S = Nx << 3;
  const int jj = flat % S, kq = flat / S;
  const int bx = jj >> 3, by = (kq << 3) + (jj & 7);
  if (by >= Mblkp) return;

  const int tid  = threadIdx.x;
  const int lane = tid & 63, wv = tid >> 6;
  const int row0 = by * 256, col0 = bx * 128;

  const unsigned short* Btu = Btp;
  const float* biasu = biasp;
  int Mu = Mp;
  int cfoff = 0;
  if (row0 >= halfRows) { Btu = Bt2; biasu = bias2; Mu = M2; cfoff = 64; }

  const int rl = lane >> 3;
  const int sS = (lane & 7) ^ rl;

  const int lr = lane & 15, lk = lane >> 4;
  const int wr = wv >> 1, wc = wv & 1;
  const int swz = lr & 7;

  f32x4 acc[4][4] = {};

  for (int k0 = 0; k0 < K; k0 += 64) {
#pragma unroll
    for (int i = 0; i < 4; i++) {          // A: 8 waves x 32 rows = 256
      size_t ga = (size_t)(row0 + wv * 32 + i * 8 + rl) * K + k0 + sS * 8;
      gload_lds16(Ap + ga, ldsA + wv * 2048 + i * 512);
    }
#pragma unroll
    for (int i = 0; i < 2; i++) {          // B: 8 waves x 16 rows = 128
      size_t gb = (size_t)(col0 + wv * 16 + i * 8 + rl) * K + k0 + sS * 8;
      gload_lds16(Btu + gb, ldsB + wv * 1024 + i * 512);
    }
    __syncthreads();
#pragma unroll
    for (int half = 0; half < 2; half++) {
      const int k8 = half * 4 + lk;
      const int so = (k8 ^ swz) << 3;
      bf16x8 av[4], bv[4];
#pragma unroll
      for (int m = 0; m < 4; m++)
        av[m] = *(const bf16x8*)&ldsA[(wr * 64 + m * 16 + lr) * 64 + so];
#pragma unroll
      for (int n = 0; n < 4; n++)
        bv[n] = *(const bf16x8*)&ldsB[(wc * 64 + n * 16 + lr) * 64 + so];
#pragma unroll
      for (int m = 0; m < 4; m++)
#pragma unroll
        for (int n = 0; n < 4; n++)
          acc[m][n] = __builtin_amdgcn_mfma_f32_16x16x32_bf16(av[m], bv[n], acc[m][n], 0, 0, 0);
    }
    __syncthreads();
  }

  if (ACT == 2) {
    __shared__ float csum[64];
    if (tid < 64) csum[tid] = 0.f;
    __syncthreads();
#pragma unroll
    for (int n = 0; n < 4; n++) {
      int col = col0 + wc * 64 + n * 16 + lr;
      if (col < Np) {
        float bi = biasu[col];
        float local = 0.f;
#pragma unroll
        for (int m = 0; m < 4; m++)
#pragma unroll
          for (int g = 0; g < 4; g++) {
            int row = row0 + wr * 64 + m * 16 + lk * 4 + g;
            if (row < Mu) local += tanhf(acc[m][n][g] + bi);
          }
        atomicAdd(&csum[col], local);
      }
    }
    __syncthreads();
    if (tid < 64) atomicAdd(&Cfp[cfoff + tid], csum[tid]);
    return;
  }

  float su = 0.f;
  if (ACT == 3) su = 1.f / (1.f + expf(-skipp[0]));
  float bi[4];
#pragma unroll
  for (int n = 0; n < 4; n++) {
    int col = col0 + wc * 64 + n * 16 + lr;
    bi[n] = (col < Np) ? biasu[col] : 0.f;
  }

#pragma unroll
  for (int ch = 0; ch < 4; ch++) {
    __syncthreads();
    if (wr == ch) {
#pragma unroll
      for (int m = 0; m < 4; m++)
#pragma unroll
        for (int n = 0; n < 4; n++) {
          int c = wc * 64 + n * 16 + lr;
          int wbase = c + 2 * (c >> 5);
#pragma unroll
          for (int g = 0; g < 4; g++) {
            int lrow = m * 16 + lk * 4 + g;
            ldsE[lrow * 134 + wbase] = acc[m][n][g] + bi[n];
          }
        }
    }
    __syncthreads();
#pragma unroll
    for (int i = 0; i < 2; i++) {
      int c = tid + i * 512;            // 0..1023 over 64 rows x 16 col-chunks
      int lrow = c >> 4, cc = c & 15;
      int row = row0 + ch * 64 + lrow;
      int colb = cc * 8;
      int base = lrow * 134 + 8 * cc + 2 * (cc >> 2);
      float v[8];
#pragma unroll
      for (int q2 = 0; q2 < 4; q2++) {
        float2 tv = *(const float2*)&ldsE[base + 2 * q2];
        v[2 * q2] = tv.x; v[2 * q2 + 1] = tv.y;
      }
      if (ACT == 1) {
#pragma unroll
        for (int q = 0; q < 8; q++) v[q] = fmaxf(v[q], 0.f);
      }
      if (ACT == 3) {
        u16x8 xp = *(const u16x8*)(xprev + (size_t)row * 256 + col0 + colb);
#pragma unroll
        for (int q = 0; q < 8; q++) v[q] = su * v[q] + (1.f - su) * b2f(xp[q]);
      }
      if (ACT == 4) {
        if (colb < 64 && row < Mu) {
          int hh = colb >> 4;
          int o0 = colb & 15;
          float s1 = 0, d1 = 0, s2 = 0, d2 = 0;
#pragma unroll
          for (int q = 0; q < 8; q++) {
            float x = v[q];
            s1 += x * as1[hh * 16 + o0 + q];
            d1 += x * ad1[hh * 16 + o0 + q];
            s2 += x * as2[hh * 16 + o0 + q];
            d2 += x * ad2[hh * 16 + o0 + q];
          }
          s1 += __shfl_xor(s1, 1); d1 += __shfl_xor(d1, 1);
          s2 += __shfl_xor(s2, 1); d2 += __shfl_xor(d2, 1);
          if ((lane & 1) == 0) {
            size_t idx = (size_t)row * 4 + hh;
            alsd[idx]           = s1;
            alsd[AL4 + idx]     = d1;
            alsd[2 * AL4 + idx] = s2;
            alsd[3 * AL4 + idx] = d2;
          }
        }
      }
      if (Cbp) {
        int col = col0 + colb;
        if (col < Np) {
          u16x8 o;
#pragma unroll
          for (int q = 0; q < 8; q++) o[q] = f2b(row < Mu ? v[q] : 0.f);
          *(u16x8*)(Cbp + (size_t)row * ldcbp + col) = o;
        }
      }
      if (Cfp && row < Mu) {
        int col = col0 + colb;
        if (col < Np)
          *(float4*)&Cfp[(size_t)row * ldcf + col] = make_float4(v[0], v[1], v[2], v[3]);
        if (col + 4 < Np)
          *(float4*)&Cfp[(size_t)row * ldcf + col + 4] = make_float4(v[4], v[5], v[6], v[7]);
      }
    }
  }
}

// ============ fused prep (block-granular; small regions FIRST, streaming conv LAST) ============
// regions: comb [0,16), bias [16,21), zero-cnt [21,139), transp [139,1323), conv [1323,7611)
__global__ __launch_bounds__(256)
void prep_all(const float* __restrict__ x_user, const float* __restrict__ x_drug,
              const float* __restrict__ x_user_ref,
              const float* __restrict__ W_in_user, const float* __restrict__ W_in_drug,
              const float* __restrict__ W_kqv_user, const float* __restrict__ W_kqv_drug,
              const float* __restrict__ W_out_user, const float* __restrict__ W_fin,
              const float* __restrict__ W_han, const float* __restrict__ Wk_sem,
              const float* __restrict__ Wk_uu, const float* __restrict__ Wv_uu,
              const float* __restrict__ Wk_du, const float* __restrict__ Wv_du,
              const float* __restrict__ b_kqv_user, const float* __restrict__ b_kqv_drug,
              unsigned short* __restrict__ xub, unsigned short* __restrict__ xdb,
              unsigned short* __restrict__ xrb,
              unsigned short* __restrict__ Btu_in, unsigned short* __restrict__ Btd_in,
              unsigned short* __restrict__ Btall_u, unsigned short* __restrict__ Btall_d,
              unsigned short* __restrict__ Bto, unsigned short* __restrict__ Btf,
              unsigned short* __restrict__ Bth, unsigned short* __restrict__ BtWk,
              float* __restrict__ ball_u, float* __restrict__ ball_d,
              int* __restrict__ cnt)
{
  __shared__ float sWh[4096];      // 16KB
  __shared__ float sWk[64][65];    // 16.6KB
  const int b = blockIdx.x;
  const int tid = threadIdx.x;

  if (b < 16) {  // comb x16: block = (mat, hh); LDS-tiled, 4 ctiles of 64 cols
    int mat = b >> 2, hh = b & 3;
    const float* Wkqv; const float* Wh; unsigned short* Bt; int coloff;
    switch (mat) {
      case 0:  Wkqv = W_kqv_user; Wh = Wk_uu; Bt = Btall_u;          coloff = 0;   break;
      case 1:  Wkqv = W_kqv_user; Wh = Wv_uu; Bt = Btall_u + 131072; coloff = 512; break;
      case 2:  Wkqv = W_kqv_drug; Wh = Wk_du; Bt = Btall_d;          coloff = 0;   break;
      default: Wkqv = W_kqv_drug; Wh = Wv_du; Bt = Btall_d + 65536;  coloff = 512; break;
    }
    for (int i = tid; i < 4096; i += 256) sWh[i] = Wh[hh * 4096 + i];
    __syncthreads();
    for (int ct = 0; ct < 4; ct++) {
      for (int i = tid; i < 4096; i += 256) {
        int cl = i >> 6, d = i & 63;
        sWk[cl][d] = Wkqv[(size_t)(ct * 64 + cl) * 768 + coloff + hh * 64 + d];
      }
      __syncthreads();
      int cl = tid & 63, eg = tid >> 6;
      float acc[16] = {};
      for (int d = 0; d < 64; d++) {
        float w = sWk[cl][d];
#pragma unroll
        for (int e = 0; e < 16; e++) acc[e] += w * sWh[d * 64 + eg * 16 + e];
      }
#pragma unroll
      for (int e = 0; e < 16; e++)
        Bt[(size_t)(hh * 64 + eg * 16 + e) * 256 + ct * 64 + cl] = f2b(acc[e]);
      __syncthreads();
    }
    return;
  }
  if (b < 21) {  // biases (5 blocks x 256 = 1280)
    int j = (b - 16) * 256 + tid;
    const float* bb; const float* Wh; float* outp; int coloff, e256;
    if (j < 256)       { outp = &ball_u[j];        bb = b_kqv_user; Wh = Wk_uu; coloff = 0;   e256 = j; }
    else if (j < 512)  { ball_u[j] = b_kqv_user[j]; return; }
    else if (j < 768)  { outp = &ball_u[j];        bb = b_kqv_user; Wh = Wv_uu; coloff = 512; e256 = j - 512; }
    else if (j < 1024) { outp = &ball_d[j - 768];  bb = b_kqv_drug; Wh = Wk_du; coloff = 0;   e256 = j - 768; }
    else               { outp = &ball_d[j - 768];  bb = b_kqv_drug; Wh = Wv_du; coloff = 512; e256 = j - 1024; }
    int hh = e256 >> 6, e = e256 & 63;
    float acc = 0.f;
    for (int d = 0; d < 64; d++)
      acc += bb[coloff + hh * 64 + d] * Wh[hh * 4096 + d * 64 + e];
    *outp = acc;
    return;
  }
  if (b < 139) {  // zero cnt (3*NU = 120000 ints -> 30000 int4 units; 118 blocks)
    int u = (b - 21) * 256 + tid;
    int idx = u * 4;
    if (idx < 3 * NU) *(int4*)&cnt[idx] = make_int4(0, 0, 0, 0);
    return;
  }
  if (b < 1323) {  // transp_conv x7 (scalar; small, L2-resident)
    size_t i = (size_t)(b - 139) * 256 + tid;
    const float* W; unsigned short* Bt; int ldw, coloff, K, N;
    if (i < 32768)       { W = W_in_user;  Bt = Btu_in;          ldw = 256; coloff = 0;   K = 128; N = 256; }
    else if (i < 65536)  { W = W_in_drug;  Bt = Btd_in;          ldw = 256; coloff = 0;   K = 128; N = 256; i -= 32768; }
    else if (i < 131072) { W = W_kqv_user; Bt = Btall_u + 65536; ldw = 768; coloff = 256; K = 256; N = 256; i -= 65536; }
    else if (i < 196608) { W = W_out_user; Bt = Bto;             ldw = 256; coloff = 0;   K = 256; N = 256; i -= 131072; }
    else if (i < 278528) { W = W_fin;      Bt = Btf;             ldw = 256; coloff = 0;   K = 320; N = 256; i -= 196608; }
    else if (i < 294912) { W = W_han;      Bt = Bth;             ldw = 64;  coloff = 0;   K = 128; N = 64;  i -= 278528; }
    else                 { W = Wk_sem;     Bt = BtWk;            ldw = 64;  coloff = 0;   K = 64;  N = 64;  i -= 294912; }
    int n = (int)(i / K), k = (int)(i - (size_t)n * K);
    Bt[i] = (n < N) ? f2b(W[(size_t)k * ldw + coloff + n]) : 0;
    return;
  }
  {  // vectorized conv_pad x3 (uniform streaming tail)
    int bc = b - 1323;
    const float* in; unsigned short* outp; int M; int bl;
    if (bc < 2512)      { in = x_user;     outp = xub; M = NU; bl = bc; }
    else if (bc < 3776) { in = x_drug;     outp = xdb; M = ND; bl = bc - 2512; }
    else                { in = x_user_ref; outp = xrb; M = NU; bl = bc - 3776; }
    size_t e0 = ((size_t)bl * 256 + tid) * 8;
    int r = (int)(e0 >> 7);
    u16x8 o;
    if (r < M) {
      float4 a = *(const float4*)(in + e0);
      float4 bb = *(const float4*)(in + e0 + 4);
      o[0] = f2b(a.x); o[1] = f2b(a.y); o[2] = f2b(a.z); o[3] = f2b(a.w);
      o[4] = f2b(bb.x); o[5] = f2b(bb.y); o[6] = f2b(bb.z); o[7] = f2b(bb.w);
    } else {
#pragma unroll
      for (int q = 0; q < 8; q++) o[q] = 0;
    }
    *(u16x8*)(outp + e0) = o;
  }
}

// ============ CSR build ============
__global__ void hist_all(const int* __restrict__ ei_du, const int* __restrict__ ei_uu,
                         const int* __restrict__ ei_r1, const int* __restrict__ ei_r2,
                         int* __restrict__ cnt)
{
  int t = blockIdx.x * 256 + threadIdx.x;
  if (t >= NEDGE) return;
  const int* ei; int* c;
  switch (blockIdx.y) {
    case 0: ei = ei_du; c = cnt; break;
    case 1: ei = ei_uu; c = cnt; break;
    case 2: ei = ei_r1; c = cnt + NU; break;
    default: ei = ei_r2; c = cnt + 2 * NU; break;
  }
  atomicAdd(&c[ei[NEDGE + t]], 1);
}

__global__ __launch_bounds__(256)
void scan_partial(const int* __restrict__ cnt, int* __restrict__ csums)
{
  int b = blockIdx.x;
  int rel = b / NCH, ch = b - rel * NCH;
  const int* c = cnt + (size_t)rel * NU;
  int t = threadIdx.x;
  int i0 = ch * CHUNK + t * 8;
  int s = 0;
#pragma unroll
  for (int j = 0; j < 8; j++) { int i = i0 + j; if (i < NU) s += c[i]; }
  __shared__ int ps[256];
  ps[t] = s;
  __syncthreads();
  for (int d = 128; d > 0; d >>= 1) { if (t < d) ps[t] += ps[t + d]; __syncthreads(); }
  if (t == 0) csums[b] = ps[0];
}

// also zeroes colpart2
__global__ void scan_mid(const int* __restrict__ csums, int* __restrict__ coffs,
                         int* __restrict__ rs, float* __restrict__ colpart2)
{
  int r = threadIdx.x;   // 128 threads
  if (r < 128) colpart2[r] = 0.f;
  if (r >= 3) return;
  int run = 0;
  for (int ch = 0; ch < NCH; ch++) { coffs[r * NCH + ch] = run; run += csums[r * NCH + ch]; }
  rs[(size_t)r * NUP + NU] = run;
}

// zeroes cnt after reading (cursor reset)
__global__ __launch_bounds__(256)
void scan_final(int* __restrict__ cnt, const int* __restrict__ coffs,
                int* __restrict__ rs)
{
  int b = blockIdx.x;
  int rel = b / NCH, ch = b - rel * NCH;
  int* c = cnt + (size_t)rel * NU;
  int* r = rs + (size_t)rel * NUP;
  int t = threadIdx.x;
  int i0 = ch * CHUNK + t * 8;
  int loc[8]; int s = 0;
#pragma unroll
  for (int j = 0; j < 8; j++) {
    int i = i0 + j;
    loc[j] = (i < NU) ? c[i] : 0;
    if (i < NU) c[i] = 0;
    s += loc[j];
  }
  __shared__ int ps[256];
  ps[t] = s;
  __syncthreads();
  for (int d = 1; d < 256; d <<= 1) {
    int o = (t >= d) ? ps[t - d] : 0;
    __syncthreads();
    ps[t] += o;
    __syncthreads();
  }
  int run = coffs[b] + ps[t] - s;
#pragma unroll
  for (int j = 0; j < 8; j++) { int i = i0 + j; if (i < NU) { r[i] = run; run += loc[j]; } }
}

// ============ merged fills: y=0 han r1, y=1 han r2, y=2 hgt du, y=3 hgt uu ============
// HGT halves are index-scatter only: esrcH[pos] = kbase|type (k-row offset
// in qukvb ushort units; type bit 0: 0=du, 1=uu). QK moved to gather.
__global__ void fill_all(const int* __restrict__ ei_r1, const int* __restrict__ ei_r2,
                         const int* __restrict__ ei_du, const int* __restrict__ ei_uu,
                         const float* __restrict__ alsd,
                         const int* __restrict__ rs, int* __restrict__ cur,
                         int* __restrict__ esrc1, float* __restrict__ aev1,
                         int* __restrict__ esrc2, float* __restrict__ aev2,
                         int* __restrict__ esrcH)
{
  int t = blockIdx.x * 256 + threadIdx.x;
  if (t >= NEDGE * 4) return;
  int y = blockIdx.y;
  int e = t >> 2, hh = t & 3;
  if (y < 2) {
    const int* ei = y ? ei_r2 : ei_r1;
    const float* als = alsd + (y ? 2 * AL4 : 0);
    const float* ald = alsd + (y ? 3 * AL4 : AL4);
    const int* rsp = rs + (size_t)(y ? 2 : 1) * NUP;
    int* curp = cur + (size_t)(y ? 2 : 1) * NU;
    int* esrc = y ? esrc2 : esrc1;
    float* aev = y ? aev2 : aev1;
    int s = ei[e], d = ei[NEDGE + e];
    float al = als[s * 4 + hh] + ald[d * 4 + hh];
    al = (al >= 0.f) ? al : 0.2f * al;
    float ex = expf(al);
    int pos = 0;
    if (hh == 0) pos = rsp[d] + atomicAdd(&curp[d], 1);
    pos = __shfl(pos, (threadIdx.x & 63) & ~3, 64);
    aev[pos * 4 + hh] = ex;
    if (hh == 0) esrc[pos] = s;
  } else {
    if (hh != 0) return;
    int yy = y - 2;
    const int* ei = yy ? ei_uu : ei_du;
    int s = ei[e], d = ei[NEDGE + e];
    int pos = rs[d] + atomicAdd(&cur[d], 1);
    int kb = yy ? ((s * 768) | 1) : (NUP * 768 + s * 512);
    esrcH[pos] = kb;
  }
}

// ============ merged gathers: y=0 obf1, y=1 obf2, y=2 hout ============
// y<2: single-pass weighted-mean, batch-4 MLP unroll (clamped indices; dead
// slots replay end-1 -> L1-hit, weight zeroed).
// y=2: fused QK dot (16-lane shuffle reduce) + softmax + PV + GELU;
//      q[d] row loaded once per wave (coalesced).
__global__ __launch_bounds__(256)
void gather_all(const int* __restrict__ rs,
                const int* __restrict__ esrc1, const float* __restrict__ aev1,
                const int* __restrict__ esrc2, const float* __restrict__ aev2,
                const int* __restrict__ esrcH,
                const unsigned short* __restrict__ hb,
                const unsigned short* __restrict__ vbase,
                const float* __restrict__ p_du, const float* __restrict__ p_uu,
                unsigned short* __restrict__ obf1, unsigned short* __restrict__ obf2,
                unsigned short* __restrict__ houtb)
{
  int gid = blockIdx.x * 256 + threadIdx.x;
  int wid = gid >> 6, lane = gid & 63;
  if (wid >= NUP) return;
  int y = blockIdx.y;
  int head = lane >> 4;
  if (y < 2) {
    const int* rsp = rs + (size_t)(y ? 2 : 1) * NUP;
    const int* esrc = y ? esrc2 : esrc1;
    const float* aev = y ? aev2 : aev1;
    unsigned short* obf = y ? obf2 : obf1;
    int beg = 0, end = 0;
    if (wid < NU) { beg = rsp[wid]; end = rsp[wid + 1]; }
    float asum = 0.f, a = 0.f;
    for (int i0 = beg; i0 < end; i0 += 4) {
      int idx[4]; float w[4];
#pragma unroll
      for (int u = 0; u < 4; u++) {
        int i = i0 + u;
        int ic = (i < end) ? i : (end - 1);
        idx[u] = esrc[ic];
        float wv = aev[ic * 4 + head];
        w[u] = (i < end) ? wv : 0.f;
      }
      float hv[4];
#pragma unroll
      for (int u = 0; u < 4; u++)
        hv[u] = b2f(hb[(size_t)idx[u] * 64 + lane]);
#pragma unroll
      for (int u = 0; u < 4; u++) { asum += w[u]; a += w[u] * hv[u]; }
    }
    a *= 1.f / (asum + 1e-16f);
    obf[(size_t)wid * 64 + lane] = f2b(fmaxf(a, 0.f));
  } else {
    int beg = 0, end = 0;
    if (wid < NU) { beg = rs[wid]; end = rs[wid + 1]; }
    // q[d] row: lane covers its head's 4 columns (coalesced, once per wave)
    ushort4 qv = *(const ushort4*)(vbase + (size_t)wid * 768 + 256 + lane * 4);
    float q0 = b2f(qv.x), q1 = b2f(qv.y), q2 = b2f(qv.z), q3 = b2f(qv.w);
    float pd = p_du[head] * 0.125f, pu = p_uu[head] * 0.125f;
    float asum = 0.f;
    float a0 = 0, a1 = 0, a2 = 0, a3 = 0;
    for (int i0 = beg; i0 < end; i0 += 4) {
      int kb[4]; int live[4];
#pragma unroll
      for (int u = 0; u < 4; u++) {
        int i = i0 + u;
        int ic = (i < end) ? i : (end - 1);
        kb[u] = esrcH[ic];
        live[u] = (i < end) ? 1 : 0;
      }
      ushort4 kk[4], vv[4];
#pragma unroll
      for (int u = 0; u < 4; u++) {
        int base = kb[u] & ~1;
        int type = kb[u] & 1;
        kk[u] = *(const ushort4*)(vbase + (size_t)base + lane * 4);
        vv[u] = *(const ushort4*)(vbase + (size_t)(base + 256 + 256 * type) + lane * 4);
      }
#pragma unroll
      for (int u = 0; u < 4; u++) {
        float part = q0 * b2f(kk[u].x) + q1 * b2f(kk[u].y)
                   + q2 * b2f(kk[u].z) + q3 * b2f(kk[u].w);
        part += __shfl_xor(part, 1, 16);
        part += __shfl_xor(part, 2, 16);
        part += __shfl_xor(part, 4, 16);
        part += __shfl_xor(part, 8, 16);
        float pp = (kb[u] & 1) ? pu : pd;
        float w = live[u] ? expf(part * pp) : 0.f;
        asum += w;
        a0 += b2f(vv[u].x) * w; a1 += b2f(vv[u].y) * w;
        a2 += b2f(vv[u].z) * w; a3 += b2f(vv[u].w) * w;
      }
    }
    float inv = 1.f / (asum + 1e-16f);
    a0 *= inv; a1 *= inv; a2 *= inv; a3 *= inv;
    ushort4 o;
    o.x = f2b(0.5f * a0 * (1.f + erff(a0 * 0.70710678118654752f)));
    o.y = f2b(0.5f * a1 * (1.f + erff(a1 * 0.70710678118654752f)));
    o.z = f2b(0.5f * a2 * (1.f + erff(a2 * 0.70710678118654752f)));
    o.w = f2b(0.5f * a3 * (1.f + erff(a3 * 0.70710678118654752f)));
    *(ushort4*)(houtb + (size_t)wid * 256 + lane * 4) = o;
  }
}

__global__ void sem_final2(const float* __restrict__ colpart2,
                           const float* __restrict__ q_sem, float* __restrict__ semv)
{
  int t = threadIdx.x;            // 128
  int j = t & 63;
  __shared__ float sv[128];
  sv[t] = colpart2[t] * q_sem[j] * (1.0f / NU);
  __syncthreads();
  if (t == 0) {
    float s0 = 0, s1 = 0;
    for (int i = 0; i < 64; i++) { s0 += sv[i]; s1 += sv[64 + i]; }
    float m = fmaxf(s0, s1);
    float e0 = expf(s0 - m), e1 = expf(s1 - m);
    semv[0] = e0 / (e0 + e1); semv[1] = e1 / (e0 + e1);
  }
}

// ============ epilogues ============
__global__ void fill_ref_b(const unsigned short* __restrict__ obf1,
                           const unsigned short* __restrict__ obf2,
                           const float* __restrict__ semv, unsigned short* __restrict__ afinb)
{
  int t = blockIdx.x * 256 + threadIdx.x;  // n*64 + j
  if (t >= NUP * 64) return;
  int n = t >> 6, j = t & 63;
  float v = semv[0] * b2f(obf1[t]) + semv[1] * b2f(obf2[t]);  // pad rows are 0
  afinb[(size_t)n * 320 + 256 + j] = f2b(v);
}

// ------------------------------------------------------------------
extern "C" void kernel_launch(void* const* d_in, const int* in_sizes, int n_in,
                              void* d_out, int out_size, void* d_ws, size_t ws_size,
                              hipStream_t stream)
{
  (void)in_sizes; (void)n_in; (void)out_size; (void)ws_size;
  const float* x_user     = (const float*)d_in[0];
  const float* x_drug     = (const float*)d_in[1];
  const float* x_user_ref = (const float*)d_in[2];
  const int*   ei_du      = (const int*)d_in[4];
  const int*   ei_uu      = (const int*)d_in[5];
  const int*   ei_r1      = (const int*)d_in[6];
  const int*   ei_r2      = (const int*)d_in[7];
  const float* W_han      = (const float*)d_in[8];
  const float* b_han      = (const float*)d_in[9];
  const float* a_src_r1   = (const float*)d_in[10];
  const float* a_dst_r1   = (const float*)d_in[11];
  const float* a_src_r2   = (const float*)d_in[12];
  const float* a_dst_r2   = (const float*)d_in[13];
  const float* Wk_sem     = (const float*)d_in[14];
  const float* bk_sem     = (const float*)d_in[15];
  const float* q_sem      = (const float*)d_in[16];
  const float* W_in_user  = (const float*)d_in[17];
  const float* b_in_user  = (const float*)d_in[18];
  const float* W_in_drug  = (const float*)d_in[19];
  const float* b_in_drug  = (const float*)d_in[20];
  const float* W_kqv_user = (const float*)d_in[21];
  const float* b_kqv_user = (const float*)d_in[22];
  const float* W_kqv_drug = (const float*)d_in[23];
  const float* b_kqv_drug = (const float*)d_in[24];
  const float* Wk_du      = (const float*)d_in[28];
  const float* Wv_du      = (const float*)d_in[29];
  const float* p_du       = (const float*)d_in[30];
  const float* Wk_uu      = (const float*)d_in[31];
  const float* Wv_uu      = (const float*)d_in[32];
  const float* p_uu       = (const float*)d_in[33];
  const float* W_out_user = (const float*)d_in[34];
  const float* b_out_user = (const float*)d_in[35];
  const float* skip_user  = (const float*)d_in[38];
  const float* W_fin      = (const float*)d_in[40];
  const float* b_fin      = (const float*)d_in[41];
  float* out = (float*)d_out;

  // ---------------- workspace ----------------
  char* base = (char*)d_ws;
  size_t off = 0;
  auto alloc = [&](size_t bytes) { char* p = base + off; off += (bytes + 255) & ~(size_t)255; return p; };

  unsigned short* hb = (unsigned short*)alloc((size_t)NUP * 64 * 2);   // bf16 h
  float* alsd    = (float*)alloc((size_t)4 * AL4 * 4);   // als1|ald1|als2|ald2
  float* colpart2= (float*)alloc(128 * 4);
  float* semv    = (float*)alloc(64);
  float* ball_u  = (float*)alloc(768 * 4);
  float* ball_d  = (float*)alloc(512 * 4);

  int* cnt   = (int*)alloc((size_t)3 * NU * 4);
  int* rs    = (int*)alloc((size_t)3 * NUP * 4);
  int* csums = (int*)alloc((size_t)3 * NCH * 4);
  int* coffs = (int*)alloc((size_t)3 * NCH * 4);
  int* esrcH = (int*)alloc((size_t)2 * NEDGE * 4);
  int* esrc1 = (int*)alloc((size_t)NEDGE * 4);
  float* aev1= (float*)alloc((size_t)NEDGE * 4 * 4);
  int* esrc2 = (int*)alloc((size_t)NEDGE * 4);
  float* aev2= (float*)alloc((size_t)NEDGE * 4 * 4);

  unsigned short* obf1 = (unsigned short*)alloc((size_t)NUP * 64 * 2);  // contiguous with obf2
  unsigned short* obf2 = (unsigned short*)alloc((size_t)NUP * 64 * 2);

  unsigned short* qukvb = (unsigned short*)alloc((size_t)NUP * 768 * 2); // contiguous with kvdb
  unsigned short* kvdb  = (unsigned short*)alloc((size_t)NDP * 512 * 2);

  unsigned short* xub2d = (unsigned short*)alloc((size_t)NUP * 256 * 2); // contiguous with xdb2d
  unsigned short* xdb2d = (unsigned short*)alloc((size_t)NDP * 256 * 2);

  unsigned short* houtb = (unsigned short*)alloc((size_t)NUP * 256 * 2);
  unsigned short* xrb   = houtb;

  unsigned short* afinb = (unsigned short*)alloc((size_t)NUP * 320 * 2);
  unsigned short* xub   = afinb;                       // rows [0,NUP)
  unsigned short* xdb   = afinb + (size_t)NUP * 128;   // rows [NUP,NUP+NDP)

  unsigned short* Btu_in  = (unsigned short*)alloc(256 * 128 * 2);
  unsigned short* Btd_in  = (unsigned short*)alloc(256 * 128 * 2);
  unsigned short* Btall_u = (unsigned short*)alloc(768 * 256 * 2);
  unsigned short* Btall_d = (unsigned short*)alloc(512 * 256 * 2);
  unsigned short* Bto     = (unsigned short*)alloc(256 * 256 * 2);
  unsigned short* Btf     = (unsigned short*)alloc(256 * 320 * 2);
  unsigned short* Bth     = (unsigned short*)alloc(128 * 128 * 2);
  unsigned short* BtWk    = (unsigned short*)alloc(128 * 64 * 2);

  dim3 blk(256), blk5(512);
  auto g1 = [](size_t n) { return dim3((unsigned)((n + 255) / 256)); };
  auto gg = [](int N, int Mblk) {   // Mblk = number of 256-row panels
    int Nx = (N + 127) / 128;
    return (unsigned)(((Mblk + 7) / 8) * 8 * Nx);
  };
  const int BIG = 1 << 30;
  const unsigned short* NB = nullptr;
  const float* NF = nullptr;
  unsigned short* NBm = nullptr;

  // ===== fused prep: comb(16)+bias(5)+zerocnt(118)+transp(1184)+conv(6288) =====
  const int prep_blocks = 16 + 5 + 118 + 1184 + 6288;
  prep_all<<<dim3(prep_blocks), blk, 0, stream>>>(
      x_user, x_drug, x_user_ref, W_in_user, W_in_drug, W_kqv_user, W_kqv_drug,
      W_out_user, W_fin, W_han, Wk_sem, Wk_uu, Wv_uu, Wk_du, Wv_du,
      b_kqv_user, b_kqv_drug,
      xub, xdb, xrb, Btu_in, Btd_in, Btall_u, Btall_d, Bto, Btf, Bth, BtWk,
      ball_u, ball_d, cnt);

  // ===== CSR build =====
  hist_all<<<dim3((NEDGE + 255) / 256, 4), blk, 0, stream>>>(ei_du, ei_uu, ei_r1, ei_r2, cnt);
  scan_partial<<<3 * NCH, blk, 0, stream>>>(cnt, csums);
  scan_mid<<<1, 128, 0, stream>>>(csums, coffs, rs, colpart2);
  scan_final<<<3 * NCH, blk, 0, stream>>>(cnt, coffs, rs);   // zeroes cnt (cursors)

  // ===== HAN branch: h-GEMM (bf16 hb out) with fused alsd (ACT=4) =====
  gemm_bf16<4><<<gg(64, 157), blk5, 0, stream>>>(
      xrb, Bth, b_han, (float*)nullptr, 0, hb, 64, NU, 64, 128, 157,
      nullptr, nullptr, BIG, NB, NF, 0,
      a_src_r1, a_dst_r1, a_src_r2, a_dst_r2, alsd,
      BIG, NB, NB, NF, NBm, 0, 0, 0, 0);

  // ===== input GEMM: dual-half (user / drug) =====
  gemm_bf16<1><<<gg(256, 236), blk5, 0, stream>>>(
      xub, Btu_in, b_in_user, (float*)nullptr, 0, xub2d, 256, NU, 256, 128, 236,
      nullptr, nullptr, NUP, Btd_in, b_in_drug, NUP + ND,
      NF, NF, NF, NF, nullptr,
      BIG, NB, NB, NF, NBm, 0, 0, 0, 0);

  // ===== merged qukv + kvd GEMM: two-range grid =====
  {
    unsigned B1 = gg(768, 157), B2 = gg(512, 79);
    gemm_bf16<0><<<dim3(B1 + B2), blk5, 0, stream>>>(
        xub2d, Btall_u, ball_u, (float*)nullptr, 0, qukvb, 768, NU, 768, 256, 157,
        nullptr, nullptr, BIG, NB, NF, 0, NF, NF, NF, NF, nullptr,
        (int)B1, xdb2d, Btall_d, ball_d, kvdb, 512, ND, 512, 79);
  }

  // ===== merged fills (han r1/r2 exp + hgt index-scatter) =====
  fill_all<<<dim3((NEDGE * 4 + 255) / 256, 4), blk, 0, stream>>>(
      ei_r1, ei_r2, ei_du, ei_uu, alsd,
      rs, cnt, esrc1, aev1, esrc2, aev2, esrcH);

  // ===== merged gathers (obf1, obf2, hout w/ fused QK-softmax-PV) =====
  gather_all<<<dim3((NUP * 64 + 255) / 256, 3), blk, 0, stream>>>(
      rs, esrc1, aev1, esrc2, aev2, esrcH, hb, qukvb, p_du, p_uu,
      obf1, obf2, houtb);

  // ===== semantic attention =====
  gemm_bf16<2><<<gg(64, 314), blk5, 0, stream>>>(
      obf1, BtWk, bk_sem, colpart2, 0, NBm, 0, NU, 64, 64, 314,
      nullptr, nullptr, NUP, BtWk, bk_sem, NUP + NU,
      NF, NF, NF, NF, nullptr,
      BIG, NB, NB, NF, NBm, 0, 0, 0, 0);
  sem_final2<<<1, 128, 0, stream>>>(colpart2, q_sem, semv);

  // ===== output head =====
  gemm_bf16<3><<<gg(256, 157), blk5, 0, stream>>>(
      houtb, Bto, b_out_user, (float*)nullptr, 0, afinb, 320, NU, 256, 256, 157,
      skip_user, xub2d, BIG, NB, NF, 0, NF, NF, NF, NF, nullptr,
      BIG, NB, NB, NF, NBm, 0, 0, 0, 0);
  fill_ref_b<<<g1((size_t)NUP * 64), blk, 0, stream>>>(obf1, obf2, semv, afinb);

  gemm_bf16<0><<<gg(256, 157), blk5, 0, stream>>>(
      afinb, Btf, b_fin, out, 256, NBm, 0, NU, 256, 320, 157,
      nullptr, nullptr, BIG, NB, NF, 0, NF, NF, NF, NF, nullptr,
      BIG, NB, NB, NF, NBm, 0, 0, 0, 0);
}